// Round 7
// baseline (335.784 us; speedup 1.0000x reference)
//
#include <hip/hip_runtime.h>

#define D_   64
#define NBT_ 12800   // B*T = 32*400
#define B_   32

typedef float v4f __attribute__((ext_vector_type(4)));

// Broadcast lane l's value of v to all lanes (SGPR result).
__device__ __forceinline__ float rl(float v, int l) {
    return __uint_as_float(__builtin_amdgcn_readlane(__float_as_uint(v), l));
}

// One wave (64 lanes) per (b,t) matrix. Lane i holds row i of sigma in 64
// VGPRs (plain float[64]; ext-vector arrays spill — r2).
//
// Measured landscape: r3 pure-LDS broadcast = exact 12cyc/op LDS roofline
// (147us). r5 hybrid (12 cols readlane, rest LDS b128) = 129us, ~80% of
// its balanced-pipe floor (~103us). r6 rank-4 = 162us (panel serial chain
// dominated). Readlane calibrates to ~10cyc per dependent RL->FMA pair;
// LDS b128 broadcast ~12cyc/4 values. Hybrid split is the right balance;
// the residual gap is SERIAL EXPOSURE: broadcasts waited on
// a = row[k]*rsqrt(s), i.e. behind readlane(diag)->rsqrt.
//
// This version decouples them algebraically:
//   - publish UNSCALED row[k] to LDS (write depends only on prev near-FMA,
//     issues ~150cy earlier; round-trip hides under diag+near phase);
//   - near-chunk readlanes take rl(row[k], j) UNSCALED (same early issue);
//   - scaling folds into the multiplier: c = row[k] * rcp(s)
//     (a*a_j = row[k]*row_j[k]/s). rcp/rsq ~1ulp — tolerance already
//     absorbs approx transcendentals (rsq/log2 in use since r0).
//   - forward substitution also scale-free: d -= row[k] * (zk*inv).
// Compiler can't do this (FP-unsafe re-association across rsqrt/rcp).
//
// Dead lanes/columns (i<k, j<=k in boundary chunks) carry garbage in
// registers never sourced by any broadcast path (broadcasts read lane j's
// column-k element, j>=k only; diag/z read lane k).
//
// __launch_bounds__(256,2): validated anti-spill setting (r4: 4.5GB spill
// without; r5/r6 clean with).
__global__ __launch_bounds__(256, 2) void chol_ll(const float* __restrict__ x,
                                                  const float* __restrict__ mu,
                                                  const float* __restrict__ sigma,
                                                  float* __restrict__ partial) {
    const int lane = threadIdx.x & 63;
    const int wv   = threadIdx.x >> 6;
    const int bt   = blockIdx.x * 4 + wv;

    __shared__ __align__(16) float colbuf[4][2][D_];   // per-wave dbuf column
    float* const cb0 = colbuf[wv][0];
    float* const cb1 = colbuf[wv][1];

    const float4* srow = (const float4*)(sigma + (size_t)bt * (D_ * D_) + (size_t)lane * D_);
    float row[D_];
    #pragma unroll
    for (int m = 0; m < D_ / 4; ++m) {
        float4 t = srow[m];
        row[4 * m + 0] = t.x; row[4 * m + 1] = t.y;
        row[4 * m + 2] = t.z; row[4 * m + 3] = t.w;
    }
    float d = x[bt * D_ + lane] - mu[bt * D_ + lane];

    float q = 0.f, lg = 0.f;
    #pragma unroll
    for (int k = 0; k < D_; ++k) {
        const int m0 = (k + 1) >> 2;                          // first live chunk
        const int ms = (m0 + 3 < D_ / 4) ? m0 + 3 : D_ / 4;   // pipe split

        // publish UNSCALED column k early (depends only on prev iter's
        // near-FMA of row[k]); double-buffered on k parity (in-order DS
        // per wave -> no cross-iteration WAR; validated r2/r3/r5).
        float* cb = (k & 1) ? cb1 : cb0;
        if (ms < D_ / 4) cb[lane] = row[k];

        // diagonal (lane k's row[k] is valid) + EPS regularization
        float s   = rl(row[k], k) + 1e-6f;
        float inv = __builtin_amdgcn_rsqf(s);   // 1/sqrt(s)
        float rc  = __builtin_amdgcn_rcpf(s);   // 1/s
        lg += __builtin_amdgcn_logf(s);         // log2(s); scaled at end
        // fused forward substitution: z_k = d_k / L[k][k]
        float zk = rl(d, k) * inv;
        q += zk * zk;
        d -= row[k] * (zk * inv);               // valid for lanes i > k
        float c = row[k] * rc;                  // update multiplier L[i][k]/L[k][k]

        // near chunks via readlane of UNSCALED row[k] (VALU pipe;
        // independent of rsq/rcp chain); dead j <= k harmless
        #pragma unroll
        for (int m = m0; m < ms; ++m) {
            row[4 * m + 0] -= c * rl(row[k], 4 * m + 0);
            row[4 * m + 1] -= c * rl(row[k], 4 * m + 1);
            row[4 * m + 2] -= c * rl(row[k], 4 * m + 2);
            row[4 * m + 3] -= c * rl(row[k], 4 * m + 3);
        }

        // far chunks via LDS uniform-address broadcast (LDS pipe)
        #pragma unroll
        for (int m = ms; m < D_ / 4; ++m) {
            v4f bc = *(const v4f*)(cb + 4 * m);
            row[4 * m + 0] -= c * bc[0];
            row[4 * m + 1] -= c * bc[1];
            row[4 * m + 2] -= c * bc[2];
            row[4 * m + 3] -= c * bc[3];
        }
    }

    if (lane == 0) {
        float log_det = 0.34657359027997264f * lg;      // 0.5 * ln(2) * sum(log2 s)
        // -0.5*sum(z^2) - log_det - 0.5*D*ln(2*pi)
        float lp = -0.5f * q - log_det - 58.81206612509905f;
        partial[bt] = lp;
    }
}

__global__ __launch_bounds__(1024) void reduce_ll(const float* __restrict__ partial,
                                                  float* __restrict__ out) {
    float s = 0.f;
    for (int i = threadIdx.x; i < NBT_; i += 1024) s += partial[i];
    #pragma unroll
    for (int off = 32; off > 0; off >>= 1) s += __shfl_down(s, off, 64);
    __shared__ float ws[16];
    const int lane = threadIdx.x & 63, w = threadIdx.x >> 6;
    if (lane == 0) ws[w] = s;
    __syncthreads();
    if (threadIdx.x == 0) {
        float t = 0.f;
        #pragma unroll
        for (int i = 0; i < 16; ++i) t += ws[i];
        out[0] = -t / (float)B_;   // out = -mean_b sum_t log_prob
    }
}

extern "C" void kernel_launch(void* const* d_in, const int* in_sizes, int n_in,
                              void* d_out, int out_size, void* d_ws, size_t ws_size,
                              hipStream_t stream) {
    const float* x     = (const float*)d_in[0];
    const float* mu    = (const float*)d_in[1];
    const float* sigma = (const float*)d_in[2];
    float* partial = (float*)d_ws;   // NBT_ floats = 51.2 KB scratch
    chol_ll<<<NBT_ / 4, 256, 0, stream>>>(x, mu, sigma, partial);
    reduce_ll<<<1, 1024, 0, stream>>>(partial, (float*)d_out);
}